// Round 21
// baseline (51.039 us; speedup 1.0000x reference)
//
#include <hip/hip_runtime.h>

#define N2 (768 * 768)
#define NH 32
#define PPB 64       // pairs per block; 9216 blocks
#define TPB 256      // 4 threads per pair, 4 waves
#define CAP 1408     // staged LDS entries; global-walk fallback beyond

typedef float v4f __attribute__((ext_vector_type(4)));

// ---------- Pass 1: parallel block-boundary search ----------
// key(e) = (coeff==0 ? INT_MAX : pair[e]) is globally sorted (pair_idx sorted
// ascending over valid prefix, padding coeff==0 at the tail). bnd[j] =
// lower_bound(key, j*PPB). 9217 independent searches, fully parallel.
__global__ void bounds_kernel(const int* __restrict__ pair,
                              const float* __restrict__ coeff,
                              int* __restrict__ bnd, int M) {
    int j = blockIdx.x * blockDim.x + threadIdx.x;
    if (j > N2 / PPB) return;
    int target = j * PPB;
    int lo = 0, hi = M;
    while (lo < hi) {
        int mid = (lo + hi) >> 1;
        int key = (coeff[mid] == 0.f) ? 0x7fffffff : pair[mid];
        if (key < target) lo = mid + 1; else hi = mid;
    }
    bnd[j] = lo;
}

// ---------- Pass 2: fused stage(+precompute) + walk + expand ----------
// out[h,p] = b[h]*S0[p] + sum_k W[h][k]*S[k][p] over pair p's entry segment.
// Staging (vectorized int4/int4/float4, window 4-aligned, M%4==0 keeps loads
// in-bounds) now ALSO gathers ea[node] (4 independent loads/group) and stages
// the precomputed per-entry contribution (c, c*ea[0..3]) -> the walk is pure
// LDS (ds_read_b128 + ds_read_b32 + adds), no dependent global gather.
// Run boundaries from registers (2 scalar neighbor loads). 4 threads/pair
// walk stride-4; 2-step shfl_xor merge; sums to dedicated LDS buffer;
// expansion = 2 v4f NT stores/thread. Every output element written exactly
// once; missing pairs keep ps=pe=0 -> exact zeros, matching segment_sum.
__global__ __launch_bounds__(256) void fused_kernel(
    const int* __restrict__ pair, const int* __restrict__ node,
    const float* __restrict__ coeff, const float* __restrict__ ea,
    const float* __restrict__ W, const float* __restrict__ bias,
    const int* __restrict__ bnd, float* __restrict__ out, int M)
{
    __shared__ v4f   entA[CAP + 4];      // c*ea[nd][0..3]  (22.6 KB)
    __shared__ float entC[CAP + 4];      // c               (5.6 KB)
    __shared__ float sum[5][PPB];        // 1.25 KB
    __shared__ int ps[PPB], pe[PPB];
    __shared__ float sW[NH * 4];
    __shared__ float sBias[NH];

    const int t = threadIdx.x;
    const int p0 = blockIdx.x * PPB;

    if (t < NH * 4) sW[t] = W[t];
    if (t < NH) sBias[t] = bias[t];
    if (t < PPB) { ps[t] = 0; pe[t] = 0; }
    __syncthreads();

    const int s0 = bnd[blockIdx.x], s1 = bnd[blockIdx.x + 1];
    const int s0a = s0 & ~3;             // 4-aligned staging base
    const int cntA = s1 - s0a;           // staged span
    const bool staged = (cntA <= CAP);   // block-uniform

    if (staged) {
        for (int i4 = t; (i4 << 2) < cntA; i4 += TPB) {
            const int e0 = s0a + (i4 << 2);
            const int i0 = i4 << 2;
            const int4   p4 = reinterpret_cast<const int4*>(pair)[e0 >> 2];
            const int4   n4 = reinterpret_cast<const int4*>(node)[e0 >> 2];
            const float4 c4 = reinterpret_cast<const float4*>(coeff)[e0 >> 2];
            // 4 independent ea gathers (pipelined; off the walk's chain)
            const float4 ex = *reinterpret_cast<const float4*>(ea + n4.x * 4);
            const float4 ey = *reinterpret_cast<const float4*>(ea + n4.y * 4);
            const float4 ez = *reinterpret_cast<const float4*>(ea + n4.z * 4);
            const float4 ew = *reinterpret_cast<const float4*>(ea + n4.w * 4);
            v4f ax; ax.x = c4.x * ex.x; ax.y = c4.x * ex.y; ax.z = c4.x * ex.z; ax.w = c4.x * ex.w;
            v4f ay; ay.x = c4.y * ey.x; ay.y = c4.y * ey.y; ay.z = c4.y * ey.z; ay.w = c4.y * ey.w;
            v4f az; az.x = c4.z * ez.x; az.y = c4.z * ez.y; az.z = c4.z * ez.z; az.w = c4.z * ez.w;
            v4f aw; aw.x = c4.w * ew.x; aw.y = c4.w * ew.y; aw.z = c4.w * ew.z; aw.w = c4.w * ew.w;
            entA[i0]     = ax; entA[i0 + 1] = ay;
            entA[i0 + 2] = az; entA[i0 + 3] = aw;
            v4f cc; cc.x = c4.x; cc.y = c4.y; cc.z = c4.z; cc.w = c4.w;
            *reinterpret_cast<v4f*>(&entC[i0]) = cc;
            // run boundaries from registers
            const int prevp = (e0 > 0) ? pair[e0 - 1] : -1;
            const int nextp = (e0 + 4 < M) ? pair[e0 + 4] : -1;
            const int pk[6] = { prevp, p4.x, p4.y, p4.z, p4.w, nextp };
#pragma unroll
            for (int j = 0; j < 4; ++j) {
                const int e = e0 + j;
                const int pp = pk[j + 1];
                if (e >= s0 && e < s1) {
                    if (e == s0 || pk[j] != pp) ps[pp - p0] = e;
                    if (e == s1 - 1 || pk[j + 2] != pp) pe[pp - p0] = e + 1;
                }
            }
        }
    } else {
        const int cnt = s1 - s0;
        for (int i = t; i < cnt; i += TPB) {
            int e = s0 + i;
            int pp = pair[e];
            if (i == 0 || pair[e - 1] != pp) ps[pp - p0] = e;
            if (i == cnt - 1 || pair[e + 1] != pp) pe[pp - p0] = e + 1;
        }
    }
    __syncthreads();

    // 4 threads per pair: q = t>>2 walks entries s+sub, s+sub+4, ... pure LDS
    const int q = t >> 2, sub = t & 3;
    float a0 = 0.f, a1 = 0.f, a2 = 0.f, a3 = 0.f, a4 = 0.f;
    {
        const int e = pe[q];
        int k = ps[q] + sub;
        if (staged) {
            for (; k < e; k += 4) {
                const v4f v = entA[k - s0a];
                const float cc = entC[k - s0a];
                a0 += cc; a1 += v.x; a2 += v.y; a3 += v.z; a4 += v.w;
            }
        } else {
            for (; k < e; k += 4) {
                const float cc = coeff[k];
                const float4 v = *reinterpret_cast<const float4*>(ea + node[k] * 4);
                a0 += cc; a1 += cc * v.x; a2 += cc * v.y; a3 += cc * v.z; a4 += cc * v.w;
            }
        }
    }
#pragma unroll
    for (int d = 1; d < 4; d <<= 1) {
        a0 += __shfl_xor(a0, d); a1 += __shfl_xor(a1, d); a2 += __shfl_xor(a2, d);
        a3 += __shfl_xor(a3, d); a4 += __shfl_xor(a4, d);
    }
    if (sub == 0) {
        sum[0][q] = a0; sum[1][q] = a1; sum[2][q] = a2;
        sum[3][q] = a3; sum[4][q] = a4;
    }
    __syncthreads();

    // expansion: wave w, lane l; group g = l&15 -> pairs 4g..4g+3;
    // channels h = w*8 + (l>>4)*2 + j, j in {0,1}.
    {
        const int l = t & 63, w = t >> 6;
        const int g = l & 15, quad = l >> 4;
        const v4f c0 = *reinterpret_cast<const v4f*>(&sum[0][4 * g]);
        const v4f c1 = *reinterpret_cast<const v4f*>(&sum[1][4 * g]);
        const v4f c2 = *reinterpret_cast<const v4f*>(&sum[2][4 * g]);
        const v4f c3 = *reinterpret_cast<const v4f*>(&sum[3][4 * g]);
        const v4f c4 = *reinterpret_cast<const v4f*>(&sum[4][4 * g]);
        const size_t op = (size_t)p0 + 4 * g;
#pragma unroll
        for (int j = 0; j < 2; ++j) {
            const int h = w * 8 + quad * 2 + j;
            const float bb = sBias[h], w0 = sW[h * 4], w1 = sW[h * 4 + 1],
                        w2 = sW[h * 4 + 2], w3 = sW[h * 4 + 3];
            v4f o = bb * c0 + w0 * c1 + w1 * c2 + w2 * c3 + w3 * c4;
            __builtin_nontemporal_store(o, reinterpret_cast<v4f*>(out + (size_t)h * N2 + op));
        }
    }
}

extern "C" void kernel_launch(void* const* d_in, const int* in_sizes, int n_in,
                              void* d_out, int out_size, void* d_ws, size_t ws_size,
                              hipStream_t stream) {
    // inputs: 0=x 1=edge_attr 2=W 3=b 4=edge_idx 5=pair_idx 6=node_idx 7=coeff 8=num_nodes
    const float* ea    = (const float*)d_in[1];
    const float* W     = (const float*)d_in[2];
    const float* b     = (const float*)d_in[3];
    const int*   pair  = (const int*)d_in[5];
    const int*   node  = (const int*)d_in[6];
    const float* coeff = (const float*)d_in[7];
    float* out = (float*)d_out;
    int M = in_sizes[5];

    int* bnd = (int*)d_ws;   // N2/PPB + 1 = 9217 ints

    bounds_kernel<<<(N2 / PPB + 1 + 255) / 256, 256, 0, stream>>>(pair, coeff, bnd, M);

    fused_kernel<<<N2 / PPB, TPB, 0, stream>>>(pair, node, coeff, ea, W, b, bnd, out, M);
}

// Round 22
// 49.104 us; speedup vs baseline: 1.0394x; 1.0394x over previous
//
#include <hip/hip_runtime.h>

#define N2 (768 * 768)
#define NH 32
#define PPW 16       // pairs per wave
#define WPB 4        // waves per block; 256 threads; 9216 blocks
#define TPB 256
#define CAPW 512     // staged entries per wave (4 KB slice)

typedef float v4f __attribute__((ext_vector_type(4)));

// ---------- Pass 1: parallel wave-boundary search ----------
// key(e) = (coeff==0 ? INT_MAX : pair[e]) is globally sorted (pair_idx sorted
// ascending over valid prefix, padding coeff==0 at the tail). bnd[j] =
// lower_bound(key, j*PPW). 36865 independent searches, fully parallel.
__global__ void bounds_kernel(const int* __restrict__ pair,
                              const float* __restrict__ coeff,
                              int* __restrict__ bnd, int M) {
    int j = blockIdx.x * blockDim.x + threadIdx.x;
    if (j > N2 / PPW) return;
    int target = j * PPW;
    int lo = 0, hi = M;
    while (lo < hi) {
        int mid = (lo + hi) >> 1;
        int key = (coeff[mid] == 0.f) ? 0x7fffffff : pair[mid];
        if (key < target) lo = mid + 1; else hi = mid;
    }
    bnd[j] = lo;
}

// ---------- Pass 2: barrier-free wave-autonomous stage+walk+expand ----------
// Each wave owns 16 pairs and a private LDS slice; no __syncthreads anywhere.
// Within a wave, LDS write->read is ordered by the instruction stream
// (compiler lgkmcnt), so stage -> walk -> merge -> expand runs at the wave's
// own pace; 32 resident waves/CU overlap phases freely. Staging: vectorized
// int4/int4/float4 (16B/lane; window 4-aligned; M%4==0 keeps loads in
// bounds), run boundaries from registers (2 scalar L1-hit neighbor loads),
// two ds_write_b128. Walk: 4 thr/pair, 2 adjacent entries/iter (stride 8),
// ea gathers L1-hot. 2-step shfl_xor merge; expansion reads W/bias from
// global (L1-hot) and writes v4f NT stores. Every output element written
// exactly once; missing pairs keep ps=pe=0 -> exact zeros (segment_sum).
__global__ __launch_bounds__(256) void fused_kernel(
    const int* __restrict__ pair, const int* __restrict__ node,
    const float* __restrict__ coeff, const float* __restrict__ ea,
    const float* __restrict__ W, const float* __restrict__ bias,
    const int* __restrict__ bnd, float* __restrict__ out, int M)
{
    __shared__ float2 ent[WPB][CAPW];    // 16 KB
    __shared__ int ps[WPB][PPW], pe[WPB][PPW];   // 512 B
    __shared__ float sum[WPB][5][PPW];   // 1.25 KB

    const int t = threadIdx.x;
    const int w = t >> 6, lane = t & 63;
    const int wv = blockIdx.x * WPB + w;
    const int p0 = wv * PPW;

    if (lane < PPW) { ps[w][lane] = 0; pe[w][lane] = 0; }   // wave-ordered

    const int s0 = bnd[wv], s1 = bnd[wv + 1];
    const int s0a = s0 & ~3;             // 4-aligned staging base
    const int cntA = s1 - s0a;
    const bool staged = (cntA <= CAPW);  // wave-uniform

    if (staged) {
        for (int i4 = lane; (i4 << 2) < cntA; i4 += 64) {
            const int e0 = s0a + (i4 << 2);
            const int4   p4 = reinterpret_cast<const int4*>(pair)[e0 >> 2];
            const int4   n4 = reinterpret_cast<const int4*>(node)[e0 >> 2];
            const float4 c4 = reinterpret_cast<const float4*>(coeff)[e0 >> 2];
            v4f w0v; w0v.x = c4.x; w0v.y = __int_as_float(n4.x);
                     w0v.z = c4.y; w0v.w = __int_as_float(n4.y);
            v4f w1v; w1v.x = c4.z; w1v.y = __int_as_float(n4.z);
                     w1v.z = c4.w; w1v.w = __int_as_float(n4.w);
            *reinterpret_cast<v4f*>(&ent[w][i4 << 2])       = w0v;
            *reinterpret_cast<v4f*>(&ent[w][(i4 << 2) + 2]) = w1v;
            const int prevp = (e0 > 0) ? pair[e0 - 1] : -1;
            const int nextp = (e0 + 4 < M) ? pair[e0 + 4] : -1;
            const int pk[6] = { prevp, p4.x, p4.y, p4.z, p4.w, nextp };
#pragma unroll
            for (int j = 0; j < 4; ++j) {
                const int e = e0 + j;
                const int pp = pk[j + 1];
                if (e >= s0 && e < s1) {     // window holds only this wave's pairs
                    if (e == s0 || pk[j] != pp) ps[w][pp - p0] = e - s0a;
                    if (e == s1 - 1 || pk[j + 2] != pp) pe[w][pp - p0] = e - s0a + 1;
                }
            }
        }
    }

    // walk: 4 threads/pair, 2 adjacent entries per iteration (stride 8)
    const int q = lane >> 2, sub = lane & 3;
    float a0 = 0.f, a1 = 0.f, a2 = 0.f, a3 = 0.f, a4 = 0.f;
    float b0s = 0.f, b1s = 0.f, b2s = 0.f, b3s = 0.f, b4s = 0.f;
    if (staged) {
        const int e = pe[w][q];
        int k = ps[w][q] + (sub << 1);
        for (; k < e; k += 8) {
            const float2 enA = ent[w][k];
            const float ccA = enA.x;
            const float4 vA = *reinterpret_cast<const float4*>(ea + __float_as_int(enA.y) * 4);
            a0 += ccA; a1 += ccA * vA.x; a2 += ccA * vA.y; a3 += ccA * vA.z; a4 += ccA * vA.w;
            if (k + 1 < e) {
                const float2 enB = ent[w][k + 1];
                const float ccB = enB.x;
                const float4 vB = *reinterpret_cast<const float4*>(ea + __float_as_int(enB.y) * 4);
                b0s += ccB; b1s += ccB * vB.x; b2s += ccB * vB.y; b3s += ccB * vB.z; b4s += ccB * vB.w;
            }
        }
    } else {
        // rare overflow: per-pair bounds via binary search, walk global
        const int tgt = p0 + q;
        int lo = s0, hi = s1;
        while (lo < hi) { int mid = (lo + hi) >> 1; if (pair[mid] < tgt) lo = mid + 1; else hi = mid; }
        const int st = lo; hi = s1;
        while (lo < hi) { int mid = (lo + hi) >> 1; if (pair[mid] <= tgt) lo = mid + 1; else hi = mid; }
        for (int k = st + (sub << 1); k < lo; k += 8) {
            const float ccA = coeff[k];
            const float4 vA = *reinterpret_cast<const float4*>(ea + node[k] * 4);
            a0 += ccA; a1 += ccA * vA.x; a2 += ccA * vA.y; a3 += ccA * vA.z; a4 += ccA * vA.w;
            if (k + 1 < lo) {
                const float ccB = coeff[k + 1];
                const float4 vB = *reinterpret_cast<const float4*>(ea + node[k + 1] * 4);
                b0s += ccB; b1s += ccB * vB.x; b2s += ccB * vB.y; b3s += ccB * vB.z; b4s += ccB * vB.w;
            }
        }
    }
    a0 += b0s; a1 += b1s; a2 += b2s; a3 += b3s; a4 += b4s;
#pragma unroll
    for (int d = 1; d < 4; d <<= 1) {
        a0 += __shfl_xor(a0, d); a1 += __shfl_xor(a1, d); a2 += __shfl_xor(a2, d);
        a3 += __shfl_xor(a3, d); a4 += __shfl_xor(a4, d);
    }
    if (sub == 0) {
        sum[w][0][q] = a0; sum[w][1][q] = a1; sum[w][2][q] = a2;
        sum[w][3][q] = a3; sum[w][4][q] = a4;
    }

    // expansion (same wave reads its own sums; ordered by instruction stream)
    // lane: g = lane&3 -> pairs 4g..4g+3; hh = lane>>2 -> channels hh, hh+16
    {
        const int g = lane & 3, hh = lane >> 2;
        const v4f c0 = *reinterpret_cast<const v4f*>(&sum[w][0][4 * g]);
        const v4f c1 = *reinterpret_cast<const v4f*>(&sum[w][1][4 * g]);
        const v4f c2 = *reinterpret_cast<const v4f*>(&sum[w][2][4 * g]);
        const v4f c3 = *reinterpret_cast<const v4f*>(&sum[w][3][4 * g]);
        const v4f c4v = *reinterpret_cast<const v4f*>(&sum[w][4][4 * g]);
        const size_t op = (size_t)p0 + 4 * g;
#pragma unroll
        for (int j = 0; j < 2; ++j) {
            const int h = hh + j * 16;
            const float4 wr = *reinterpret_cast<const float4*>(W + h * 4);  // L1-hot
            const float bb = bias[h];
            v4f o = bb * c0 + wr.x * c1 + wr.y * c2 + wr.z * c3 + wr.w * c4v;
            __builtin_nontemporal_store(o, reinterpret_cast<v4f*>(out + (size_t)h * N2 + op));
        }
    }
}

extern "C" void kernel_launch(void* const* d_in, const int* in_sizes, int n_in,
                              void* d_out, int out_size, void* d_ws, size_t ws_size,
                              hipStream_t stream) {
    // inputs: 0=x 1=edge_attr 2=W 3=b 4=edge_idx 5=pair_idx 6=node_idx 7=coeff 8=num_nodes
    const float* ea    = (const float*)d_in[1];
    const float* W     = (const float*)d_in[2];
    const float* b     = (const float*)d_in[3];
    const int*   pair  = (const int*)d_in[5];
    const int*   node  = (const int*)d_in[6];
    const float* coeff = (const float*)d_in[7];
    float* out = (float*)d_out;
    int M = in_sizes[5];

    int* bnd = (int*)d_ws;   // N2/PPW + 1 = 36865 ints

    bounds_kernel<<<(N2 / PPW + 1 + 255) / 256, 256, 0, stream>>>(pair, coeff, bnd, M);

    fused_kernel<<<N2 / (PPW * WPB), TPB, 0, stream>>>(pair, node, coeff, ea, W, b, bnd, out, M);
}